// Round 29
// baseline (182.417 us; speedup 1.0000x reference)
//
#include <hip/hip_runtime.h>
#include <math.h>

#define NB 4
#define SL 1024
#define DM 1024
#define NH 16
#define HD 64

typedef short v8s __attribute__((ext_vector_type(8)));
typedef float v4f __attribute__((ext_vector_type(4)));
typedef float v8f __attribute__((ext_vector_type(8)));
typedef unsigned short u16;
typedef unsigned int u32;

__device__ __forceinline__ v4f mfma_bf16(v8s a, v8s b, v4f c) {
  return __builtin_amdgcn_mfma_f32_16x16x32_bf16(a, b, c, 0, 0, 0);
}
__device__ __forceinline__ float bf2f(u16 x) {
  union { unsigned int u; float f; } cv; cv.u = ((unsigned int)x) << 16; return cv.f;
}
__device__ __forceinline__ u16 f2bf(float f) {
  union { float f; unsigned int u; } cv; cv.f = f;
  unsigned int r = cv.u + 0x7FFFu + ((cv.u >> 16) & 1u);
  return (u16)(r >> 16);
}
__device__ __forceinline__ v8s cvt8h(const float* p) {
  v8f x = *reinterpret_cast<const v8f*>(p);
  v8s h;
#pragma unroll
  for (int j = 0; j < 8; ++j) h[j] = (short)f2bf(x[j]);
  return h;
}
__device__ __forceinline__ void gl16(const u16* g, u16* lds_base_uniform) {
  __builtin_amdgcn_global_load_lds(
      (const __attribute__((address_space(1))) u32*)g,
      (__attribute__((address_space(3))) u32*)lds_base_uniform, 16, 0, 0);
}

// merged weight convert: w_qs,w_ks,w_vs,fc_w -> bf16
__global__ __launch_bounds__(256) void cvt_w4(
    const float* __restrict__ wq, const float* __restrict__ wk,
    const float* __restrict__ wv, const float* __restrict__ fw,
    u16* __restrict__ wqb, u16* __restrict__ wkb, u16* __restrict__ wvb,
    u16* __restrict__ fwb) {
  const unsigned total = 4u << 18;
  for (unsigned g = blockIdx.x * 256 + threadIdx.x; g < total;
       g += gridDim.x * 256) {
    unsigned r = g >> 18, local = g & ((1u << 18) - 1), i = local * 4;
    const float* src = (r == 0) ? wq : (r == 1) ? wk : (r == 2) ? wv : fw;
    u16* dst = (r == 0) ? wqb : (r == 1) ? wkb : (r == 2) ? wvb : fwb;
    float4 x = *reinterpret_cast<const float4*>(src + i);
    ushort4 h;
    h.x = f2bf(x.x); h.y = f2bf(x.y); h.z = f2bf(x.z); h.w = f2bf(x.w);
    *reinterpret_cast<ushort4*>(dst + i) = h;
  }
}

// ---------- projection GEMM: reg-staged f32 A (fused cvt) + gl16 B ----------
__global__ __launch_bounds__(256) void gemm_proj(
    const float* __restrict__ qf, const float* __restrict__ kf,
    const float* __restrict__ vf, const u16* __restrict__ wqb,
    const u16* __restrict__ wkb, const u16* __restrict__ wvb,
    const float* __restrict__ b_qs, const float* __restrict__ b_ks,
    const float* __restrict__ b_vs, const int* __restrict__ seq_len,
    u16* __restrict__ qh, u16* __restrict__ kh, u16* __restrict__ vt) {
  __shared__ u16 As[128 * 32];
  __shared__ u16 Bs[128 * 32];
  const int bid = blockIdx.x;
  const int sel = bid >> 8;                // 0=q,1=k,2=v
  const int tb = bid & 255;
  const int row0 = (tb >> 3) * 128;
  const int col0 = (tb & 7) * 128;
  const int bb = row0 >> 10, pos0 = row0 & (SL - 1);
  const bool dead = pos0 >= seq_len[bb];

  const int tid = threadIdx.x;
  const int wid = tid >> 6, l = tid & 63, lo4 = l & 15, hi2 = l >> 4;
  const int wm = wid >> 1, wn = wid & 1;

  v4f acc[4][4];
#pragma unroll
  for (int i = 0; i < 4; ++i)
#pragma unroll
    for (int j = 0; j < 4; ++j) acc[i][j] = (v4f){0.f, 0.f, 0.f, 0.f};

  if (!dead) {
    const float* Xf = (sel == 0) ? qf : (sel == 1) ? kf : vf;
    const u16* Wb = (sel == 0) ? wqb : (sel == 1) ? wkb : wvb;
    const int r0s = tid >> 2, c0s = (tid & 3) * 8;
    const int r1s = (tid + 256) >> 2;
    const int ub0 = (wid * 64) * 8;
    const int ub1 = (256 + wid * 64) * 8;
    for (int ks = 0; ks < 32; ++ks) {
      const int k0 = ks * 32;
      gl16(Wb + (size_t)(col0 + r0s) * DM + k0 + c0s, Bs + ub0);
      gl16(Wb + (size_t)(col0 + r1s) * DM + k0 + c0s, Bs + ub1);
      *(v8s*)&As[tid * 8] = cvt8h(Xf + (size_t)(row0 + r0s) * DM + k0 + c0s);
      *(v8s*)&As[(tid + 256) * 8] =
          cvt8h(Xf + (size_t)(row0 + r1s) * DM + k0 + c0s);
      __syncthreads();
      v8s af[4], bf[4];
#pragma unroll
      for (int mi = 0; mi < 4; ++mi)
        af[mi] = *(const v8s*)&As[(wm * 64 + mi * 16 + lo4) * 32 + hi2 * 8];
#pragma unroll
      for (int ni = 0; ni < 4; ++ni)
        bf[ni] = *(const v8s*)&Bs[(wn * 64 + ni * 16 + lo4) * 32 + hi2 * 8];
#pragma unroll
      for (int mi = 0; mi < 4; ++mi)
#pragma unroll
        for (int ni = 0; ni < 4; ++ni)
          acc[mi][ni] = mfma_bf16(af[mi], bf[ni], acc[mi][ni]);
      __syncthreads();
    }
  }

  const float* bias = (sel == 0) ? b_qs : (sel == 1) ? b_ks : b_vs;
#pragma unroll
  for (int mi = 0; mi < 4; ++mi)
#pragma unroll
    for (int ni = 0; ni < 4; ++ni)
#pragma unroll
      for (int r = 0; r < 4; ++r) {
        int row = row0 + wm * 64 + mi * 16 + hi2 * 4 + r;
        int col = col0 + wn * 64 + ni * 16 + lo4;
        u16 ob = dead ? (u16)0 : f2bf(acc[mi][ni][r] + bias[col]);
        int b_ = row >> 10, pos = row & (SL - 1);
        int h = col >> 6, d = col & (HD - 1);
        if (sel < 2) {
          u16* out = sel ? kh : qh;
          out[((size_t)(b_ * NH + h) * SL + pos) * HD + d] = ob;
        } else {
          vt[((size_t)(b_ * NH + h) * HD + d) * SL + pos] = ob;
        }
      }
}

// ---------- attention; grid = (qt, bh) for K/V L2 locality ----------
__global__ __launch_bounds__(256) void attn_kernel(
    const u16* __restrict__ qh, const u16* __restrict__ kh,
    const u16* __restrict__ vt, const int* __restrict__ seq_len,
    float* __restrict__ attn_out, float* __restrict__ ctx) {
  const int qt = blockIdx.x;
  const int bh = blockIdx.y;
  const int b_ = bh >> 4, h = bh & 15;
  const int seqb = seq_len[b_];
  const int tid = threadIdx.x;

  float* aout = attn_out + ((size_t)(h * NB + b_) * SL + qt * 16) * SL;

  if (qt * 16 >= seqb) {
    const float4 z = make_float4(0.f, 0.f, 0.f, 0.f);
#pragma unroll
    for (int i = 0; i < 16; ++i) {
      int idx = (tid + i * 256) * 4;
      int row = idx >> 10, key = idx & 1023;
      *reinterpret_cast<float4*>(&aout[(size_t)row * SL + key]) = z;
    }
    int r2 = tid >> 4, c2 = (tid & 15) * 4;
    *reinterpret_cast<float4*>(
        &ctx[((size_t)b_ * SL + qt * 16 + r2) * DM + h * HD + c2]) = z;
    return;
  }

  const int wv = tid >> 6, l = tid & 63;
  const int lo4 = l & 15, hi2 = l >> 4;

  __shared__ u16 p_lds[16][1032];
  __shared__ float red_m[4][16];
  __shared__ float red_s[4][16];

  const u16* qp = qh + ((size_t)bh * SL + qt * 16 + lo4) * HD + hi2 * 8;
  v8s aq0 = *(const v8s*)(qp);
  v8s aq1 = *(const v8s*)(qp + 32);

  const int kbase = wv * 256;
  const u16* Kb = kh + (size_t)bh * SL * HD;

  v4f s[16];
#pragma unroll
  for (int kt = 0; kt < 16; ++kt) {
    const bool kact = (kbase + kt * 16) < seqb;
    v4f acc = (v4f){0.f, 0.f, 0.f, 0.f};
    int key = kbase + kt * 16 + lo4;
    if (kact) {
      const u16* kp = Kb + key * HD + hi2 * 8;
      v8s bk0 = *(const v8s*)kp;
      v8s bk1 = *(const v8s*)(kp + 32);
      acc = mfma_bf16(aq0, bk0, acc);
      acc = mfma_bf16(aq1, bk1, acc);
    }
    bool km = key >= seqb;
#pragma unroll
    for (int r = 0; r < 4; ++r)
      s[kt][r] = km ? -INFINITY : acc[r] * 0.125f;
  }

  float m[4];
#pragma unroll
  for (int r = 0; r < 4; ++r) {
    float mm = s[0][r];
#pragma unroll
    for (int kt = 1; kt < 16; ++kt) mm = fmaxf(mm, s[kt][r]);
    for (int d2 = 1; d2 < 16; d2 <<= 1) mm = fmaxf(mm, __shfl_xor(mm, d2));
    m[r] = mm;
  }
  if (lo4 == 0) {
#pragma unroll
    for (int r = 0; r < 4; ++r) red_m[wv][hi2 * 4 + r] = m[r];
  }
  __syncthreads();
#pragma unroll
  for (int r = 0; r < 4; ++r) {
    float mm = red_m[0][hi2 * 4 + r];
    mm = fmaxf(mm, red_m[1][hi2 * 4 + r]);
    mm = fmaxf(mm, red_m[2][hi2 * 4 + r]);
    mm = fmaxf(mm, red_m[3][hi2 * 4 + r]);
    m[r] = mm;
  }
  float sm[4] = {0.f, 0.f, 0.f, 0.f};
#pragma unroll
  for (int kt = 0; kt < 16; ++kt) {
#pragma unroll
    for (int r = 0; r < 4; ++r) {
      float p = __expf(s[kt][r] - m[r]);
      s[kt][r] = p;
      sm[r] += p;
    }
  }
#pragma unroll
  for (int r = 0; r < 4; ++r)
    for (int d2 = 1; d2 < 16; d2 <<= 1) sm[r] += __shfl_xor(sm[r], d2);
  if (lo4 == 0) {
#pragma unroll
    for (int r = 0; r < 4; ++r) red_s[wv][hi2 * 4 + r] = sm[r];
  }
  __syncthreads();
  float inv[4];
#pragma unroll
  for (int r = 0; r < 4; ++r) {
    float t = red_s[0][hi2 * 4 + r] + red_s[1][hi2 * 4 + r] +
              red_s[2][hi2 * 4 + r] + red_s[3][hi2 * 4 + r];
    inv[r] = 1.f / t;
  }
#pragma unroll
  for (int r = 0; r < 4; ++r) {
    int row = hi2 * 4 + r;
    bool qm = (qt * 16 + row) >= seqb;
    float sc = qm ? 0.f : inv[r];
#pragma unroll
    for (int kt = 0; kt < 16; ++kt) {
      int key = kbase + kt * 16 + lo4;
      p_lds[row][key] = f2bf(s[kt][r] * sc);
    }
  }
  __syncthreads();
#pragma unroll
  for (int i = 0; i < 16; ++i) {
    int idx = (tid + i * 256) * 4;
    int row = idx >> 10, key = idx & 1023;
    ushort4 pv = *(const ushort4*)&p_lds[row][key];
    float4 o4 = make_float4(bf2f(pv.x), bf2f(pv.y), bf2f(pv.z), bf2f(pv.w));
    *reinterpret_cast<float4*>(&aout[(size_t)row * SL + key]) = o4;
  }
  v4f o = (v4f){0.f, 0.f, 0.f, 0.f};
  const u16* vbase = vt + (size_t)bh * HD * SL + (wv * 16 + lo4) * SL + hi2 * 8;
#pragma unroll 8
  for (int c = 0; c < 32; ++c) {
    if (c * 32 < seqb) {
      v8s pa = *(const v8s*)&p_lds[lo4][c * 32 + hi2 * 8];
      v8s vb = *(const v8s*)(vbase + c * 32);
      o = mfma_bf16(pa, vb, o);
    }
  }
#pragma unroll
  for (int r = 0; r < 4; ++r) {
    int row = qt * 16 + hi2 * 4 + r;
    ctx[((size_t)b_ * SL + row) * DM + h * HD + wv * 16 + lo4] = o[r];
  }
}

// ---------- fc GEMM with dead-row fast path ----------
__global__ __launch_bounds__(256) void gemm_fc(
    const float* __restrict__ ctx, const u16* __restrict__ fcwb,
    const float* __restrict__ fcb, const float* __restrict__ resid,
    const int* __restrict__ seq_len, float* __restrict__ fcout) {
  __shared__ u16 As[128 * 32];
  __shared__ u16 Bs[128 * 32];
  const int row0 = (blockIdx.x >> 3) * 128;
  const int col0 = (blockIdx.x & 7) * 128;
  const int bb = row0 >> 10, pos0 = row0 & (SL - 1);
  const bool dead = pos0 >= seq_len[bb];
  const int tid = threadIdx.x;
  const int wid = tid >> 6, l = tid & 63, lo4 = l & 15, hi2 = l >> 4;
  const int wm = wid >> 1, wn = wid & 1;

  v4f acc[4][4];
#pragma unroll
  for (int i = 0; i < 4; ++i)
#pragma unroll
    for (int j = 0; j < 4; ++j) acc[i][j] = (v4f){0.f, 0.f, 0.f, 0.f};

  if (!dead) {
    const int r0s = tid >> 2, c0s = (tid & 3) * 8;
    const int r1s = (tid + 256) >> 2;
    const int ub0 = (wid * 64) * 8;
    const int ub1 = (256 + wid * 64) * 8;
    for (int ks = 0; ks < 32; ++ks) {
      const int k0 = ks * 32;
      gl16(fcwb + (size_t)(col0 + r0s) * DM + k0 + c0s, Bs + ub0);
      gl16(fcwb + (size_t)(col0 + r1s) * DM + k0 + c0s, Bs + ub1);
      *(v8s*)&As[tid * 8] = cvt8h(ctx + (size_t)(row0 + r0s) * DM + k0 + c0s);
      *(v8s*)&As[(tid + 256) * 8] =
          cvt8h(ctx + (size_t)(row0 + r1s) * DM + k0 + c0s);
      __syncthreads();
      v8s af[4], bf[4];
#pragma unroll
      for (int mi = 0; mi < 4; ++mi)
        af[mi] = *(const v8s*)&As[(wm * 64 + mi * 16 + lo4) * 32 + hi2 * 8];
#pragma unroll
      for (int ni = 0; ni < 4; ++ni)
        bf[ni] = *(const v8s*)&Bs[(wn * 64 + ni * 16 + lo4) * 32 + hi2 * 8];
#pragma unroll
      for (int mi = 0; mi < 4; ++mi)
#pragma unroll
        for (int ni = 0; ni < 4; ++ni)
          acc[mi][ni] = mfma_bf16(af[mi], bf[ni], acc[mi][ni]);
      __syncthreads();
    }
  }
#pragma unroll
  for (int mi = 0; mi < 4; ++mi)
#pragma unroll
    for (int ni = 0; ni < 4; ++ni)
#pragma unroll
      for (int r = 0; r < 4; ++r) {
        int row = row0 + wm * 64 + mi * 16 + hi2 * 4 + r;
        int col = col0 + wn * 64 + ni * 16 + lo4;
        fcout[(size_t)row * DM + col] =
            acc[mi][ni][r] + fcb[col] + resid[(size_t)row * DM + col];
      }
}

// ---------- row LayerNorm ----------
__global__ __launch_bounds__(256) void ln_rows(
    const float* __restrict__ x, const float* __restrict__ lng,
    const float* __restrict__ lnb, float* __restrict__ out) {
  const int row = blockIdx.x * 4 + (threadIdx.x >> 6);
  const int l = threadIdx.x & 63;
  const float* xr = x + (size_t)row * DM;
  float4 v[4];
  float s = 0.f, q2 = 0.f;
#pragma unroll
  for (int j = 0; j < 4; ++j) {
    v[j] = *reinterpret_cast<const float4*>(xr + l * 4 + j * 256);
    s += v[j].x + v[j].y + v[j].z + v[j].w;
    q2 += v[j].x * v[j].x + v[j].y * v[j].y + v[j].z * v[j].z + v[j].w * v[j].w;
  }
#pragma unroll
  for (int d = 1; d < 64; d <<= 1) {
    s += __shfl_xor(s, d);
    q2 += __shfl_xor(q2, d);
  }
  const float mean = s * (1.f / DM);
  const float var = q2 * (1.f / DM) - mean * mean;
  const float rstd = rsqrtf(var + 1e-5f);
#pragma unroll
  for (int j = 0; j < 4; ++j) {
    int c = l * 4 + j * 256;
    float4 g = *reinterpret_cast<const float4*>(lng + c);
    float4 b = *reinterpret_cast<const float4*>(lnb + c);
    float4 y;
    y.x = (v[j].x - mean) * rstd * g.x + b.x;
    y.y = (v[j].y - mean) * rstd * g.y + b.y;
    y.z = (v[j].z - mean) * rstd * g.z + b.z;
    y.w = (v[j].w - mean) * rstd * g.w + b.w;
    *reinterpret_cast<float4*>(out + (size_t)row * DM + c) = y;
  }
}

extern "C" void kernel_launch(void* const* d_in, const int* in_sizes, int n_in,
                              void* d_out, int out_size, void* d_ws, size_t ws_size,
                              hipStream_t stream) {
  const float* q = (const float*)d_in[0];
  const float* k = (const float*)d_in[1];
  const float* v = (const float*)d_in[2];
  const int* seq_len = (const int*)d_in[3];
  const float* w_qs = (const float*)d_in[4];
  const float* b_qs = (const float*)d_in[5];
  const float* w_ks = (const float*)d_in[6];
  const float* b_ks = (const float*)d_in[7];
  const float* w_vs = (const float*)d_in[8];
  const float* b_vs = (const float*)d_in[9];
  const float* fcw = (const float*)d_in[10];
  const float* fcb = (const float*)d_in[11];
  const float* lng = (const float*)d_in[12];
  const float* lnb = (const float*)d_in[13];

  float* out0 = (float*)d_out;
  float* attn_out = out0 + (size_t)NB * SL * DM;

  const size_t PLANE = (size_t)NB * SL * DM;
  const size_t WSZ = (size_t)DM * DM;
  u16* wsu = (u16*)d_ws;
  u16* qh = wsu;
  u16* kh = wsu + PLANE;
  u16* vt = wsu + 2 * PLANE;
  u16* fcwb = wsu + 3 * PLANE;
  float* ctx = out0;

  // scratch in the not-yet-written attn f32 region (weights only now)
  u16* satt = (u16*)attn_out;
  u16* wqb = satt;
  u16* wkb = satt + WSZ;
  u16* wvb = satt + 2 * WSZ;

  float* fcout = (float*)d_ws;   // qh/kh dead post-attn

  cvt_w4<<<1024, 256, 0, stream>>>(w_qs, w_ks, w_vs, fcw, wqb, wkb, wvb, fcwb);
  gemm_proj<<<768, 256, 0, stream>>>(q, k, v, wqb, wkb, wvb,
                                     b_qs, b_ks, b_vs, seq_len, qh, kh, vt);
  attn_kernel<<<dim3(64, 64), 256, 0, stream>>>(qh, kh, vt, seq_len, attn_out, ctx);
  gemm_fc<<<256, 256, 0, stream>>>(ctx, fcwb, fcb, q, seq_len, fcout);
  ln_rows<<<1024, 256, 0, stream>>>(fcout, lng, lnb, out0);
}

// Round 30
// 177.726 us; speedup vs baseline: 1.0264x; 1.0264x over previous
//
#include <hip/hip_runtime.h>
#include <math.h>

#define NB 4
#define SL 1024
#define DM 1024
#define NH 16
#define HD 64

typedef short v8s __attribute__((ext_vector_type(8)));
typedef float v4f __attribute__((ext_vector_type(4)));
typedef float v8f __attribute__((ext_vector_type(8)));
typedef unsigned short u16;
typedef unsigned int u32;

__device__ __forceinline__ v4f mfma_bf16(v8s a, v8s b, v4f c) {
  return __builtin_amdgcn_mfma_f32_16x16x32_bf16(a, b, c, 0, 0, 0);
}
__device__ __forceinline__ float bf2f(u16 x) {
  union { unsigned int u; float f; } cv; cv.u = ((unsigned int)x) << 16; return cv.f;
}
__device__ __forceinline__ u16 f2bf(float f) {
  union { float f; unsigned int u; } cv; cv.f = f;
  unsigned int r = cv.u + 0x7FFFu + ((cv.u >> 16) & 1u);
  return (u16)(r >> 16);
}
__device__ __forceinline__ v8s cvt8h(const float* p) {
  v8f x = *reinterpret_cast<const v8f*>(p);
  v8s h;
#pragma unroll
  for (int j = 0; j < 8; ++j) h[j] = (short)f2bf(x[j]);
  return h;
}
__device__ __forceinline__ void gl16(const u16* g, u16* lds_base_uniform) {
  __builtin_amdgcn_global_load_lds(
      (const __attribute__((address_space(1))) u32*)g,
      (__attribute__((address_space(3))) u32*)lds_base_uniform, 16, 0, 0);
}

// ---------- merged pre-convert: q,k,v -> single bf16 planes ----------
__global__ __launch_bounds__(256) void cvt_qkv(
    const float* __restrict__ q, const float* __restrict__ k,
    const float* __restrict__ v, u16* __restrict__ qxb,
    u16* __restrict__ kxb, u16* __restrict__ vxb) {
  const unsigned total = 3u << 20;
  for (unsigned g = blockIdx.x * 256 + threadIdx.x; g < total;
       g += gridDim.x * 256) {
    unsigned r = g >> 20, local = g & ((1u << 20) - 1), i = local * 4;
    const float* src = (r == 0) ? q : (r == 1) ? k : v;
    u16* dst = (r == 0) ? qxb : (r == 1) ? kxb : vxb;
    float4 x = *reinterpret_cast<const float4*>(src + i);
    ushort4 h;
    h.x = f2bf(x.x); h.y = f2bf(x.y); h.z = f2bf(x.z); h.w = f2bf(x.w);
    *reinterpret_cast<ushort4*>(dst + i) = h;
  }
}
__global__ __launch_bounds__(256) void cvt_w4(
    const float* __restrict__ wq, const float* __restrict__ wk,
    const float* __restrict__ wv, const float* __restrict__ fw,
    u16* __restrict__ wqb, u16* __restrict__ wkb, u16* __restrict__ wvb,
    u16* __restrict__ fwb) {
  const unsigned total = 4u << 18;
  for (unsigned g = blockIdx.x * 256 + threadIdx.x; g < total;
       g += gridDim.x * 256) {
    unsigned r = g >> 18, local = g & ((1u << 18) - 1), i = local * 4;
    const float* src = (r == 0) ? wq : (r == 1) ? wk : (r == 2) ? wv : fw;
    u16* dst = (r == 0) ? wqb : (r == 1) ? wkb : (r == 2) ? wvb : fwb;
    float4 x = *reinterpret_cast<const float4*>(src + i);
    ushort4 h;
    h.x = f2bf(x.x); h.y = f2bf(x.y); h.z = f2bf(x.z); h.w = f2bf(x.w);
    *reinterpret_cast<ushort4*>(dst + i) = h;
  }
}

// ---------- projection GEMM with dead-row-tile zero-fill (r28) ----------
__global__ __launch_bounds__(256) void gemm_proj(
    const u16* __restrict__ qxb, const u16* __restrict__ kxb,
    const u16* __restrict__ vxb, const u16* __restrict__ wqb,
    const u16* __restrict__ wkb, const u16* __restrict__ wvb,
    const float* __restrict__ b_qs, const float* __restrict__ b_ks,
    const float* __restrict__ b_vs, const int* __restrict__ seq_len,
    u16* __restrict__ qh, u16* __restrict__ kh, u16* __restrict__ vt) {
  __shared__ u16 As[128 * 32];
  __shared__ u16 Bs[128 * 32];
  const int bid = blockIdx.x;
  const int sel = bid >> 8;                // 0=q,1=k,2=v
  const int tb = bid & 255;
  const int row0 = (tb >> 3) * 128;
  const int col0 = (tb & 7) * 128;
  const int bb = row0 >> 10, pos0 = row0 & (SL - 1);
  const bool dead = pos0 >= seq_len[bb];

  const int tid = threadIdx.x;
  const int wid = tid >> 6, l = tid & 63, lo4 = l & 15, hi2 = l >> 4;
  const int wm = wid >> 1, wn = wid & 1;

  v4f acc[4][4];
#pragma unroll
  for (int i = 0; i < 4; ++i)
#pragma unroll
    for (int j = 0; j < 4; ++j) acc[i][j] = (v4f){0.f, 0.f, 0.f, 0.f};

  if (!dead) {
    const u16* Xb = (sel == 0) ? qxb : (sel == 1) ? kxb : vxb;
    const u16* Wb = (sel == 0) ? wqb : (sel == 1) ? wkb : wvb;
    const int r0s = tid >> 2, c0s = (tid & 3) * 8;
    const int r1s = (tid + 256) >> 2;
    const int ub0 = (wid * 64) * 8;
    const int ub1 = (256 + wid * 64) * 8;
    for (int ks = 0; ks < 32; ++ks) {
      const int k0 = ks * 32;
      gl16(Xb + (size_t)(row0 + r0s) * DM + k0 + c0s, As + ub0);
      gl16(Xb + (size_t)(row0 + r1s) * DM + k0 + c0s, As + ub1);
      gl16(Wb + (size_t)(col0 + r0s) * DM + k0 + c0s, Bs + ub0);
      gl16(Wb + (size_t)(col0 + r1s) * DM + k0 + c0s, Bs + ub1);
      __syncthreads();
      v8s af[4], bf[4];
#pragma unroll
      for (int mi = 0; mi < 4; ++mi)
        af[mi] = *(const v8s*)&As[(wm * 64 + mi * 16 + lo4) * 32 + hi2 * 8];
#pragma unroll
      for (int ni = 0; ni < 4; ++ni)
        bf[ni] = *(const v8s*)&Bs[(wn * 64 + ni * 16 + lo4) * 32 + hi2 * 8];
#pragma unroll
      for (int mi = 0; mi < 4; ++mi)
#pragma unroll
        for (int ni = 0; ni < 4; ++ni)
          acc[mi][ni] = mfma_bf16(af[mi], bf[ni], acc[mi][ni]);
      __syncthreads();
    }
  }

  const float* bias = (sel == 0) ? b_qs : (sel == 1) ? b_ks : b_vs;
#pragma unroll
  for (int mi = 0; mi < 4; ++mi)
#pragma unroll
    for (int ni = 0; ni < 4; ++ni)
#pragma unroll
      for (int r = 0; r < 4; ++r) {
        int row = row0 + wm * 64 + mi * 16 + hi2 * 4 + r;
        int col = col0 + wn * 64 + ni * 16 + lo4;
        u16 ob = dead ? (u16)0 : f2bf(acc[mi][ni][r] + bias[col]);
        int b_ = row >> 10, pos = row & (SL - 1);
        int h = col >> 6, d = col & (HD - 1);
        if (sel < 2) {
          u16* out = sel ? kh : qh;
          out[((size_t)(b_ * NH + h) * SL + pos) * HD + d] = ob;
        } else {
          vt[((size_t)(b_ * NH + h) * HD + d) * SL + pos] = ob;
        }
      }
}

// ---------- attention; grid = (qt, bh) for K/V L2 locality ----------
__global__ __launch_bounds__(256) void attn_kernel(
    const u16* __restrict__ qh, const u16* __restrict__ kh,
    const u16* __restrict__ vt, const int* __restrict__ seq_len,
    float* __restrict__ attn_out, float* __restrict__ ctx) {
  const int qt = blockIdx.x;
  const int bh = blockIdx.y;
  const int b_ = bh >> 4, h = bh & 15;
  const int seqb = seq_len[b_];
  const int tid = threadIdx.x;

  float* aout = attn_out + ((size_t)(h * NB + b_) * SL + qt * 16) * SL;

  if (qt * 16 >= seqb) {
    const float4 z = make_float4(0.f, 0.f, 0.f, 0.f);
#pragma unroll
    for (int i = 0; i < 16; ++i) {
      int idx = (tid + i * 256) * 4;
      int row = idx >> 10, key = idx & 1023;
      *reinterpret_cast<float4*>(&aout[(size_t)row * SL + key]) = z;
    }
    int r2 = tid >> 4, c2 = (tid & 15) * 4;
    *reinterpret_cast<float4*>(
        &ctx[((size_t)b_ * SL + qt * 16 + r2) * DM + h * HD + c2]) = z;
    return;
  }

  const int wv = tid >> 6, l = tid & 63;
  const int lo4 = l & 15, hi2 = l >> 4;

  __shared__ u16 p_lds[16][1032];
  __shared__ float red_m[4][16];
  __shared__ float red_s[4][16];

  const u16* qp = qh + ((size_t)bh * SL + qt * 16 + lo4) * HD + hi2 * 8;
  v8s aq0 = *(const v8s*)(qp);
  v8s aq1 = *(const v8s*)(qp + 32);

  const int kbase = wv * 256;
  const u16* Kb = kh + (size_t)bh * SL * HD;

  v4f s[16];
#pragma unroll
  for (int kt = 0; kt < 16; ++kt) {
    const bool kact = (kbase + kt * 16) < seqb;
    v4f acc = (v4f){0.f, 0.f, 0.f, 0.f};
    int key = kbase + kt * 16 + lo4;
    if (kact) {
      const u16* kp = Kb + key * HD + hi2 * 8;
      v8s bk0 = *(const v8s*)kp;
      v8s bk1 = *(const v8s*)(kp + 32);
      acc = mfma_bf16(aq0, bk0, acc);
      acc = mfma_bf16(aq1, bk1, acc);
    }
    bool km = key >= seqb;
#pragma unroll
    for (int r = 0; r < 4; ++r)
      s[kt][r] = km ? -INFINITY : acc[r] * 0.125f;
  }

  float m[4];
#pragma unroll
  for (int r = 0; r < 4; ++r) {
    float mm = s[0][r];
#pragma unroll
    for (int kt = 1; kt < 16; ++kt) mm = fmaxf(mm, s[kt][r]);
    for (int d2 = 1; d2 < 16; d2 <<= 1) mm = fmaxf(mm, __shfl_xor(mm, d2));
    m[r] = mm;
  }
  if (lo4 == 0) {
#pragma unroll
    for (int r = 0; r < 4; ++r) red_m[wv][hi2 * 4 + r] = m[r];
  }
  __syncthreads();
#pragma unroll
  for (int r = 0; r < 4; ++r) {
    float mm = red_m[0][hi2 * 4 + r];
    mm = fmaxf(mm, red_m[1][hi2 * 4 + r]);
    mm = fmaxf(mm, red_m[2][hi2 * 4 + r]);
    mm = fmaxf(mm, red_m[3][hi2 * 4 + r]);
    m[r] = mm;
  }
  float sm[4] = {0.f, 0.f, 0.f, 0.f};
#pragma unroll
  for (int kt = 0; kt < 16; ++kt) {
#pragma unroll
    for (int r = 0; r < 4; ++r) {
      float p = __expf(s[kt][r] - m[r]);
      s[kt][r] = p;
      sm[r] += p;
    }
  }
#pragma unroll
  for (int r = 0; r < 4; ++r)
    for (int d2 = 1; d2 < 16; d2 <<= 1) sm[r] += __shfl_xor(sm[r], d2);
  if (lo4 == 0) {
#pragma unroll
    for (int r = 0; r < 4; ++r) red_s[wv][hi2 * 4 + r] = sm[r];
  }
  __syncthreads();
  float inv[4];
#pragma unroll
  for (int r = 0; r < 4; ++r) {
    float t = red_s[0][hi2 * 4 + r] + red_s[1][hi2 * 4 + r] +
              red_s[2][hi2 * 4 + r] + red_s[3][hi2 * 4 + r];
    inv[r] = 1.f / t;
  }
#pragma unroll
  for (int r = 0; r < 4; ++r) {
    int row = hi2 * 4 + r;
    bool qm = (qt * 16 + row) >= seqb;
    float sc = qm ? 0.f : inv[r];
#pragma unroll
    for (int kt = 0; kt < 16; ++kt) {
      int key = kbase + kt * 16 + lo4;
      p_lds[row][key] = f2bf(s[kt][r] * sc);
    }
  }
  __syncthreads();
#pragma unroll
  for (int i = 0; i < 16; ++i) {
    int idx = (tid + i * 256) * 4;
    int row = idx >> 10, key = idx & 1023;
    ushort4 pv = *(const ushort4*)&p_lds[row][key];
    float4 o4 = make_float4(bf2f(pv.x), bf2f(pv.y), bf2f(pv.z), bf2f(pv.w));
    *reinterpret_cast<float4*>(&aout[(size_t)row * SL + key]) = o4;
  }
  v4f o = (v4f){0.f, 0.f, 0.f, 0.f};
  const u16* vbase = vt + (size_t)bh * HD * SL + (wv * 16 + lo4) * SL + hi2 * 8;
#pragma unroll 8
  for (int c = 0; c < 32; ++c) {
    if (c * 32 < seqb) {
      v8s pa = *(const v8s*)&p_lds[lo4][c * 32 + hi2 * 8];
      v8s vb = *(const v8s*)(vbase + c * 32);
      o = mfma_bf16(pa, vb, o);
    }
  }
#pragma unroll
  for (int r = 0; r < 4; ++r) {
    int row = qt * 16 + hi2 * 4 + r;
    ctx[((size_t)b_ * SL + row) * DM + h * HD + wv * 16 + lo4] = o[r];
  }
}

// ---------- fc GEMM with dead-row fast path ----------
__global__ __launch_bounds__(256) void gemm_fc(
    const float* __restrict__ ctx, const u16* __restrict__ fcwb,
    const float* __restrict__ fcb, const float* __restrict__ resid,
    const int* __restrict__ seq_len, float* __restrict__ fcout) {
  __shared__ u16 As[128 * 32];
  __shared__ u16 Bs[128 * 32];
  const int row0 = (blockIdx.x >> 3) * 128;
  const int col0 = (blockIdx.x & 7) * 128;
  const int bb = row0 >> 10, pos0 = row0 & (SL - 1);
  const bool dead = pos0 >= seq_len[bb];
  const int tid = threadIdx.x;
  const int wid = tid >> 6, l = tid & 63, lo4 = l & 15, hi2 = l >> 4;
  const int wm = wid >> 1, wn = wid & 1;

  v4f acc[4][4];
#pragma unroll
  for (int i = 0; i < 4; ++i)
#pragma unroll
    for (int j = 0; j < 4; ++j) acc[i][j] = (v4f){0.f, 0.f, 0.f, 0.f};

  if (!dead) {
    const int r0s = tid >> 2, c0s = (tid & 3) * 8;
    const int r1s = (tid + 256) >> 2;
    const int ub0 = (wid * 64) * 8;
    const int ub1 = (256 + wid * 64) * 8;
    for (int ks = 0; ks < 32; ++ks) {
      const int k0 = ks * 32;
      gl16(fcwb + (size_t)(col0 + r0s) * DM + k0 + c0s, Bs + ub0);
      gl16(fcwb + (size_t)(col0 + r1s) * DM + k0 + c0s, Bs + ub1);
      *(v8s*)&As[tid * 8] = cvt8h(ctx + (size_t)(row0 + r0s) * DM + k0 + c0s);
      *(v8s*)&As[(tid + 256) * 8] =
          cvt8h(ctx + (size_t)(row0 + r1s) * DM + k0 + c0s);
      __syncthreads();
      v8s af[4], bf[4];
#pragma unroll
      for (int mi = 0; mi < 4; ++mi)
        af[mi] = *(const v8s*)&As[(wm * 64 + mi * 16 + lo4) * 32 + hi2 * 8];
#pragma unroll
      for (int ni = 0; ni < 4; ++ni)
        bf[ni] = *(const v8s*)&Bs[(wn * 64 + ni * 16 + lo4) * 32 + hi2 * 8];
#pragma unroll
      for (int mi = 0; mi < 4; ++mi)
#pragma unroll
        for (int ni = 0; ni < 4; ++ni)
          acc[mi][ni] = mfma_bf16(af[mi], bf[ni], acc[mi][ni]);
      __syncthreads();
    }
  }
#pragma unroll
  for (int mi = 0; mi < 4; ++mi)
#pragma unroll
    for (int ni = 0; ni < 4; ++ni)
#pragma unroll
      for (int r = 0; r < 4; ++r) {
        int row = row0 + wm * 64 + mi * 16 + hi2 * 4 + r;
        int col = col0 + wn * 64 + ni * 16 + lo4;
        fcout[(size_t)row * DM + col] =
            acc[mi][ni][r] + fcb[col] + resid[(size_t)row * DM + col];
      }
}

// ---------- row LayerNorm ----------
__global__ __launch_bounds__(256) void ln_rows(
    const float* __restrict__ x, const float* __restrict__ lng,
    const float* __restrict__ lnb, float* __restrict__ out) {
  const int row = blockIdx.x * 4 + (threadIdx.x >> 6);
  const int l = threadIdx.x & 63;
  const float* xr = x + (size_t)row * DM;
  float4 v[4];
  float s = 0.f, q2 = 0.f;
#pragma unroll
  for (int j = 0; j < 4; ++j) {
    v[j] = *reinterpret_cast<const float4*>(xr + l * 4 + j * 256);
    s += v[j].x + v[j].y + v[j].z + v[j].w;
    q2 += v[j].x * v[j].x + v[j].y * v[j].y + v[j].z * v[j].z + v[j].w * v[j].w;
  }
#pragma unroll
  for (int d = 1; d < 64; d <<= 1) {
    s += __shfl_xor(s, d);
    q2 += __shfl_xor(q2, d);
  }
  const float mean = s * (1.f / DM);
  const float var = q2 * (1.f / DM) - mean * mean;
  const float rstd = rsqrtf(var + 1e-5f);
#pragma unroll
  for (int j = 0; j < 4; ++j) {
    int c = l * 4 + j * 256;
    float4 g = *reinterpret_cast<const float4*>(lng + c);
    float4 b = *reinterpret_cast<const float4*>(lnb + c);
    float4 y;
    y.x = (v[j].x - mean) * rstd * g.x + b.x;
    y.y = (v[j].y - mean) * rstd * g.y + b.y;
    y.z = (v[j].z - mean) * rstd * g.z + b.z;
    y.w = (v[j].w - mean) * rstd * g.w + b.w;
    *reinterpret_cast<float4*>(out + (size_t)row * DM + c) = y;
  }
}

extern "C" void kernel_launch(void* const* d_in, const int* in_sizes, int n_in,
                              void* d_out, int out_size, void* d_ws, size_t ws_size,
                              hipStream_t stream) {
  const float* q = (const float*)d_in[0];
  const float* k = (const float*)d_in[1];
  const float* v = (const float*)d_in[2];
  const int* seq_len = (const int*)d_in[3];
  const float* w_qs = (const float*)d_in[4];
  const float* b_qs = (const float*)d_in[5];
  const float* w_ks = (const float*)d_in[6];
  const float* b_ks = (const float*)d_in[7];
  const float* w_vs = (const float*)d_in[8];
  const float* b_vs = (const float*)d_in[9];
  const float* fcw = (const float*)d_in[10];
  const float* fcb = (const float*)d_in[11];
  const float* lng = (const float*)d_in[12];
  const float* lnb = (const float*)d_in[13];

  float* out0 = (float*)d_out;
  float* attn_out = out0 + (size_t)NB * SL * DM;

  const size_t PLANE = (size_t)NB * SL * DM;
  const size_t WSZ = (size_t)DM * DM;
  u16* wsu = (u16*)d_ws;
  u16* qh = wsu;
  u16* kh = wsu + PLANE;
  u16* vt = wsu + 2 * PLANE;
  u16* fcwb = wsu + 3 * PLANE;
  float* ctx = out0;

  u16* satt = (u16*)attn_out;
  u16* qxb = satt;
  u16* kxb = satt + PLANE;
  u16* vxb = satt + 2 * PLANE;
  u16* wqb = satt + 3 * PLANE;
  u16* wkb = satt + 3 * PLANE + WSZ;
  u16* wvb = satt + 3 * PLANE + 2 * WSZ;

  float* fcout = (float*)d_ws;

  cvt_qkv<<<3072, 256, 0, stream>>>(q, k, v, qxb, kxb, vxb);
  cvt_w4<<<1024, 256, 0, stream>>>(w_qs, w_ks, w_vs, fcw, wqb, wkb, wvb, fcwb);
  gemm_proj<<<768, 256, 0, stream>>>(qxb, kxb, vxb, wqb, wkb, wvb,
                                     b_qs, b_ks, b_vs, seq_len, qh, kh, vt);
  attn_kernel<<<dim3(64, 64), 256, 0, stream>>>(qh, kh, vt, seq_len, attn_out, ctx);
  gemm_fc<<<256, 256, 0, stream>>>(ctx, fcwb, fcb, q, seq_len, fcout);
  ln_rows<<<1024, 256, 0, stream>>>(fcout, lng, lnb, out0);
}

// Round 31
// 165.988 us; speedup vs baseline: 1.0990x; 1.0707x over previous
//
#include <hip/hip_runtime.h>
#include <math.h>

#define NB 4
#define SL 1024
#define DM 1024
#define NH 16
#define HD 64

typedef short v8s __attribute__((ext_vector_type(8)));
typedef float v4f __attribute__((ext_vector_type(4)));
typedef float v8f __attribute__((ext_vector_type(8)));
typedef unsigned short u16;
typedef unsigned int u32;

__device__ __forceinline__ v4f mfma_bf16(v8s a, v8s b, v4f c) {
  return __builtin_amdgcn_mfma_f32_16x16x32_bf16(a, b, c, 0, 0, 0);
}
__device__ __forceinline__ float bf2f(u16 x) {
  union { unsigned int u; float f; } cv; cv.u = ((unsigned int)x) << 16; return cv.f;
}
__device__ __forceinline__ u16 f2bf(float f) {
  union { float f; unsigned int u; } cv; cv.f = f;
  unsigned int r = cv.u + 0x7FFFu + ((cv.u >> 16) & 1u);
  return (u16)(r >> 16);
}
__device__ __forceinline__ v8s cvt8h(const float* p) {
  v8f x = *reinterpret_cast<const v8f*>(p);
  v8s h;
#pragma unroll
  for (int j = 0; j < 8; ++j) h[j] = (short)f2bf(x[j]);
  return h;
}
__device__ __forceinline__ void gl16(const u16* g, u16* lds_base_uniform) {
  __builtin_amdgcn_global_load_lds(
      (const __attribute__((address_space(1))) u32*)g,
      (__attribute__((address_space(3))) u32*)lds_base_uniform, 16, 0, 0);
}

// ---------- single merged pre-convert: q,k,v + 4 weights -> bf16 ----------
// 4M float4 units total: [0,3M) = q/k/v planes, [3M,4M) = wq/wk/wv/fw.
__global__ __launch_bounds__(256) void cvt_all(
    const float* __restrict__ q, const float* __restrict__ k,
    const float* __restrict__ v, const float* __restrict__ wq,
    const float* __restrict__ wk, const float* __restrict__ wv,
    const float* __restrict__ fw, u16* __restrict__ qxb,
    u16* __restrict__ kxb, u16* __restrict__ vxb, u16* __restrict__ wqb,
    u16* __restrict__ wkb, u16* __restrict__ wvb, u16* __restrict__ fwb) {
  const unsigned total = 4u << 20;
  for (unsigned g = blockIdx.x * 256 + threadIdx.x; g < total;
       g += gridDim.x * 256) {
    const float* src;
    u16* dst;
    unsigned off;
    if (g < (3u << 20)) {
      unsigned r = g >> 20;
      off = (g & ((1u << 20) - 1)) * 4;
      src = (r == 0) ? q : (r == 1) ? k : v;
      dst = (r == 0) ? qxb : (r == 1) ? kxb : vxb;
    } else {
      unsigned g2 = g - (3u << 20);
      unsigned r = g2 >> 18;
      off = (g2 & ((1u << 18) - 1)) * 4;
      src = (r == 0) ? wq : (r == 1) ? wk : (r == 2) ? wv : fw;
      dst = (r == 0) ? wqb : (r == 1) ? wkb : (r == 2) ? wvb : fwb;
    }
    float4 x = *reinterpret_cast<const float4*>(src + off);
    ushort4 h;
    h.x = f2bf(x.x); h.y = f2bf(x.y); h.z = f2bf(x.z); h.w = f2bf(x.w);
    *reinterpret_cast<ushort4*>(dst + off) = h;
  }
}

// ---------- projection GEMM with dead-row-tile zero-fill (r28) ----------
__global__ __launch_bounds__(256) void gemm_proj(
    const u16* __restrict__ qxb, const u16* __restrict__ kxb,
    const u16* __restrict__ vxb, const u16* __restrict__ wqb,
    const u16* __restrict__ wkb, const u16* __restrict__ wvb,
    const float* __restrict__ b_qs, const float* __restrict__ b_ks,
    const float* __restrict__ b_vs, const int* __restrict__ seq_len,
    u16* __restrict__ qh, u16* __restrict__ kh, u16* __restrict__ vt) {
  __shared__ u16 As[128 * 32];
  __shared__ u16 Bs[128 * 32];
  const int bid = blockIdx.x;
  const int sel = bid >> 8;                // 0=q,1=k,2=v
  const int tb = bid & 255;
  const int row0 = (tb >> 3) * 128;
  const int col0 = (tb & 7) * 128;
  const int bb = row0 >> 10, pos0 = row0 & (SL - 1);
  const bool dead = pos0 >= seq_len[bb];

  const int tid = threadIdx.x;
  const int wid = tid >> 6, l = tid & 63, lo4 = l & 15, hi2 = l >> 4;
  const int wm = wid >> 1, wn = wid & 1;

  v4f acc[4][4];
#pragma unroll
  for (int i = 0; i < 4; ++i)
#pragma unroll
    for (int j = 0; j < 4; ++j) acc[i][j] = (v4f){0.f, 0.f, 0.f, 0.f};

  if (!dead) {
    const u16* Xb = (sel == 0) ? qxb : (sel == 1) ? kxb : vxb;
    const u16* Wb = (sel == 0) ? wqb : (sel == 1) ? wkb : wvb;
    const int r0s = tid >> 2, c0s = (tid & 3) * 8;
    const int r1s = (tid + 256) >> 2;
    const int ub0 = (wid * 64) * 8;
    const int ub1 = (256 + wid * 64) * 8;
    for (int ks = 0; ks < 32; ++ks) {
      const int k0 = ks * 32;
      gl16(Xb + (size_t)(row0 + r0s) * DM + k0 + c0s, As + ub0);
      gl16(Xb + (size_t)(row0 + r1s) * DM + k0 + c0s, As + ub1);
      gl16(Wb + (size_t)(col0 + r0s) * DM + k0 + c0s, Bs + ub0);
      gl16(Wb + (size_t)(col0 + r1s) * DM + k0 + c0s, Bs + ub1);
      __syncthreads();
      v8s af[4], bf[4];
#pragma unroll
      for (int mi = 0; mi < 4; ++mi)
        af[mi] = *(const v8s*)&As[(wm * 64 + mi * 16 + lo4) * 32 + hi2 * 8];
#pragma unroll
      for (int ni = 0; ni < 4; ++ni)
        bf[ni] = *(const v8s*)&Bs[(wn * 64 + ni * 16 + lo4) * 32 + hi2 * 8];
#pragma unroll
      for (int mi = 0; mi < 4; ++mi)
#pragma unroll
        for (int ni = 0; ni < 4; ++ni)
          acc[mi][ni] = mfma_bf16(af[mi], bf[ni], acc[mi][ni]);
      __syncthreads();
    }
  }

  const float* bias = (sel == 0) ? b_qs : (sel == 1) ? b_ks : b_vs;
#pragma unroll
  for (int mi = 0; mi < 4; ++mi)
#pragma unroll
    for (int ni = 0; ni < 4; ++ni)
#pragma unroll
      for (int r = 0; r < 4; ++r) {
        int row = row0 + wm * 64 + mi * 16 + hi2 * 4 + r;
        int col = col0 + wn * 64 + ni * 16 + lo4;
        u16 ob = dead ? (u16)0 : f2bf(acc[mi][ni][r] + bias[col]);
        int b_ = row >> 10, pos = row & (SL - 1);
        int h = col >> 6, d = col & (HD - 1);
        if (sel < 2) {
          u16* out = sel ? kh : qh;
          out[((size_t)(b_ * NH + h) * SL + pos) * HD + d] = ob;
        } else {
          vt[((size_t)(b_ * NH + h) * HD + d) * SL + pos] = ob;
        }
      }
}

// ---------- attention (r28 exact: grid = (bh, qt)) ----------
__global__ __launch_bounds__(256) void attn_kernel(
    const u16* __restrict__ qh, const u16* __restrict__ kh,
    const u16* __restrict__ vt, const int* __restrict__ seq_len,
    float* __restrict__ attn_out, float* __restrict__ ctx) {
  const int bh = blockIdx.x;
  const int qt = blockIdx.y;
  const int b_ = bh >> 4, h = bh & 15;
  const int seqb = seq_len[b_];
  const int tid = threadIdx.x;

  float* aout = attn_out + ((size_t)(h * NB + b_) * SL + qt * 16) * SL;

  if (qt * 16 >= seqb) {
    const float4 z = make_float4(0.f, 0.f, 0.f, 0.f);
#pragma unroll
    for (int i = 0; i < 16; ++i) {
      int idx = (tid + i * 256) * 4;
      int row = idx >> 10, key = idx & 1023;
      *reinterpret_cast<float4*>(&aout[(size_t)row * SL + key]) = z;
    }
    int r2 = tid >> 4, c2 = (tid & 15) * 4;
    *reinterpret_cast<float4*>(
        &ctx[((size_t)b_ * SL + qt * 16 + r2) * DM + h * HD + c2]) = z;
    return;
  }

  const int wv = tid >> 6, l = tid & 63;
  const int lo4 = l & 15, hi2 = l >> 4;

  __shared__ u16 p_lds[16][1032];
  __shared__ float red_m[4][16];
  __shared__ float red_s[4][16];

  const u16* qp = qh + ((size_t)bh * SL + qt * 16 + lo4) * HD + hi2 * 8;
  v8s aq0 = *(const v8s*)(qp);
  v8s aq1 = *(const v8s*)(qp + 32);

  const int kbase = wv * 256;
  const u16* Kb = kh + (size_t)bh * SL * HD;

  v4f s[16];
#pragma unroll
  for (int kt = 0; kt < 16; ++kt) {
    const bool kact = (kbase + kt * 16) < seqb;
    v4f acc = (v4f){0.f, 0.f, 0.f, 0.f};
    int key = kbase + kt * 16 + lo4;
    if (kact) {
      const u16* kp = Kb + key * HD + hi2 * 8;
      v8s bk0 = *(const v8s*)kp;
      v8s bk1 = *(const v8s*)(kp + 32);
      acc = mfma_bf16(aq0, bk0, acc);
      acc = mfma_bf16(aq1, bk1, acc);
    }
    bool km = key >= seqb;
#pragma unroll
    for (int r = 0; r < 4; ++r)
      s[kt][r] = km ? -INFINITY : acc[r] * 0.125f;
  }

  float m[4];
#pragma unroll
  for (int r = 0; r < 4; ++r) {
    float mm = s[0][r];
#pragma unroll
    for (int kt = 1; kt < 16; ++kt) mm = fmaxf(mm, s[kt][r]);
    for (int d2 = 1; d2 < 16; d2 <<= 1) mm = fmaxf(mm, __shfl_xor(mm, d2));
    m[r] = mm;
  }
  if (lo4 == 0) {
#pragma unroll
    for (int r = 0; r < 4; ++r) red_m[wv][hi2 * 4 + r] = m[r];
  }
  __syncthreads();
#pragma unroll
  for (int r = 0; r < 4; ++r) {
    float mm = red_m[0][hi2 * 4 + r];
    mm = fmaxf(mm, red_m[1][hi2 * 4 + r]);
    mm = fmaxf(mm, red_m[2][hi2 * 4 + r]);
    mm = fmaxf(mm, red_m[3][hi2 * 4 + r]);
    m[r] = mm;
  }
  float sm[4] = {0.f, 0.f, 0.f, 0.f};
#pragma unroll
  for (int kt = 0; kt < 16; ++kt) {
#pragma unroll
    for (int r = 0; r < 4; ++r) {
      float p = __expf(s[kt][r] - m[r]);
      s[kt][r] = p;
      sm[r] += p;
    }
  }
#pragma unroll
  for (int r = 0; r < 4; ++r)
    for (int d2 = 1; d2 < 16; d2 <<= 1) sm[r] += __shfl_xor(sm[r], d2);
  if (lo4 == 0) {
#pragma unroll
    for (int r = 0; r < 4; ++r) red_s[wv][hi2 * 4 + r] = sm[r];
  }
  __syncthreads();
  float inv[4];
#pragma unroll
  for (int r = 0; r < 4; ++r) {
    float t = red_s[0][hi2 * 4 + r] + red_s[1][hi2 * 4 + r] +
              red_s[2][hi2 * 4 + r] + red_s[3][hi2 * 4 + r];
    inv[r] = 1.f / t;
  }
#pragma unroll
  for (int r = 0; r < 4; ++r) {
    int row = hi2 * 4 + r;
    bool qm = (qt * 16 + row) >= seqb;
    float sc = qm ? 0.f : inv[r];
#pragma unroll
    for (int kt = 0; kt < 16; ++kt) {
      int key = kbase + kt * 16 + lo4;
      p_lds[row][key] = f2bf(s[kt][r] * sc);
    }
  }
  __syncthreads();
#pragma unroll
  for (int i = 0; i < 16; ++i) {
    int idx = (tid + i * 256) * 4;
    int row = idx >> 10, key = idx & 1023;
    ushort4 pv = *(const ushort4*)&p_lds[row][key];
    float4 o4 = make_float4(bf2f(pv.x), bf2f(pv.y), bf2f(pv.z), bf2f(pv.w));
    *reinterpret_cast<float4*>(&aout[(size_t)row * SL + key]) = o4;
  }
  v4f o = (v4f){0.f, 0.f, 0.f, 0.f};
  const u16* vbase = vt + (size_t)bh * HD * SL + (wv * 16 + lo4) * SL + hi2 * 8;
#pragma unroll 8
  for (int c = 0; c < 32; ++c) {
    if (c * 32 < seqb) {
      v8s pa = *(const v8s*)&p_lds[lo4][c * 32 + hi2 * 8];
      v8s vb = *(const v8s*)(vbase + c * 32);
      o = mfma_bf16(pa, vb, o);
    }
  }
#pragma unroll
  for (int r = 0; r < 4; ++r) {
    int row = qt * 16 + hi2 * 4 + r;
    ctx[((size_t)b_ * SL + row) * DM + h * HD + wv * 16 + lo4] = o[r];
  }
}

// ---------- fc GEMM with dead-row fast path ----------
__global__ __launch_bounds__(256) void gemm_fc(
    const float* __restrict__ ctx, const u16* __restrict__ fcwb,
    const float* __restrict__ fcb, const float* __restrict__ resid,
    const int* __restrict__ seq_len, float* __restrict__ fcout) {
  __shared__ u16 As[128 * 32];
  __shared__ u16 Bs[128 * 32];
  const int row0 = (blockIdx.x >> 3) * 128;
  const int col0 = (blockIdx.x & 7) * 128;
  const int bb = row0 >> 10, pos0 = row0 & (SL - 1);
  const bool dead = pos0 >= seq_len[bb];
  const int tid = threadIdx.x;
  const int wid = tid >> 6, l = tid & 63, lo4 = l & 15, hi2 = l >> 4;
  const int wm = wid >> 1, wn = wid & 1;

  v4f acc[4][4];
#pragma unroll
  for (int i = 0; i < 4; ++i)
#pragma unroll
    for (int j = 0; j < 4; ++j) acc[i][j] = (v4f){0.f, 0.f, 0.f, 0.f};

  if (!dead) {
    const int r0s = tid >> 2, c0s = (tid & 3) * 8;
    const int r1s = (tid + 256) >> 2;
    const int ub0 = (wid * 64) * 8;
    const int ub1 = (256 + wid * 64) * 8;
    for (int ks = 0; ks < 32; ++ks) {
      const int k0 = ks * 32;
      gl16(fcwb + (size_t)(col0 + r0s) * DM + k0 + c0s, Bs + ub0);
      gl16(fcwb + (size_t)(col0 + r1s) * DM + k0 + c0s, Bs + ub1);
      *(v8s*)&As[tid * 8] = cvt8h(ctx + (size_t)(row0 + r0s) * DM + k0 + c0s);
      *(v8s*)&As[(tid + 256) * 8] =
          cvt8h(ctx + (size_t)(row0 + r1s) * DM + k0 + c0s);
      __syncthreads();
      v8s af[4], bf[4];
#pragma unroll
      for (int mi = 0; mi < 4; ++mi)
        af[mi] = *(const v8s*)&As[(wm * 64 + mi * 16 + lo4) * 32 + hi2 * 8];
#pragma unroll
      for (int ni = 0; ni < 4; ++ni)
        bf[ni] = *(const v8s*)&Bs[(wn * 64 + ni * 16 + lo4) * 32 + hi2 * 8];
#pragma unroll
      for (int mi = 0; mi < 4; ++mi)
#pragma unroll
        for (int ni = 0; ni < 4; ++ni)
          acc[mi][ni] = mfma_bf16(af[mi], bf[ni], acc[mi][ni]);
      __syncthreads();
    }
  }
#pragma unroll
  for (int mi = 0; mi < 4; ++mi)
#pragma unroll
    for (int ni = 0; ni < 4; ++ni)
#pragma unroll
      for (int r = 0; r < 4; ++r) {
        int row = row0 + wm * 64 + mi * 16 + hi2 * 4 + r;
        int col = col0 + wn * 64 + ni * 16 + lo4;
        fcout[(size_t)row * DM + col] =
            acc[mi][ni][r] + fcb[col] + resid[(size_t)row * DM + col];
      }
}

// ---------- row LayerNorm ----------
__global__ __launch_bounds__(256) void ln_rows(
    const float* __restrict__ x, const float* __restrict__ lng,
    const float* __restrict__ lnb, float* __restrict__ out) {
  const int row = blockIdx.x * 4 + (threadIdx.x >> 6);
  const int l = threadIdx.x & 63;
  const float* xr = x + (size_t)row * DM;
  float4 v[4];
  float s = 0.f, q2 = 0.f;
#pragma unroll
  for (int j = 0; j < 4; ++j) {
    v[j] = *reinterpret_cast<const float4*>(xr + l * 4 + j * 256);
    s += v[j].x + v[j].y + v[j].z + v[j].w;
    q2 += v[j].x * v[j].x + v[j].y * v[j].y + v[j].z * v[j].z + v[j].w * v[j].w;
  }
#pragma unroll
  for (int d = 1; d < 64; d <<= 1) {
    s += __shfl_xor(s, d);
    q2 += __shfl_xor(q2, d);
  }
  const float mean = s * (1.f / DM);
  const float var = q2 * (1.f / DM) - mean * mean;
  const float rstd = rsqrtf(var + 1e-5f);
#pragma unroll
  for (int j = 0; j < 4; ++j) {
    int c = l * 4 + j * 256;
    float4 g = *reinterpret_cast<const float4*>(lng + c);
    float4 b = *reinterpret_cast<const float4*>(lnb + c);
    float4 y;
    y.x = (v[j].x - mean) * rstd * g.x + b.x;
    y.y = (v[j].y - mean) * rstd * g.y + b.y;
    y.z = (v[j].z - mean) * rstd * g.z + b.z;
    y.w = (v[j].w - mean) * rstd * g.w + b.w;
    *reinterpret_cast<float4*>(out + (size_t)row * DM + c) = y;
  }
}

extern "C" void kernel_launch(void* const* d_in, const int* in_sizes, int n_in,
                              void* d_out, int out_size, void* d_ws, size_t ws_size,
                              hipStream_t stream) {
  const float* q = (const float*)d_in[0];
  const float* k = (const float*)d_in[1];
  const float* v = (const float*)d_in[2];
  const int* seq_len = (const int*)d_in[3];
  const float* w_qs = (const float*)d_in[4];
  const float* b_qs = (const float*)d_in[5];
  const float* w_ks = (const float*)d_in[6];
  const float* b_ks = (const float*)d_in[7];
  const float* w_vs = (const float*)d_in[8];
  const float* b_vs = (const float*)d_in[9];
  const float* fcw = (const float*)d_in[10];
  const float* fcb = (const float*)d_in[11];
  const float* lng = (const float*)d_in[12];
  const float* lnb = (const float*)d_in[13];

  float* out0 = (float*)d_out;
  float* attn_out = out0 + (size_t)NB * SL * DM;

  const size_t PLANE = (size_t)NB * SL * DM;
  const size_t WSZ = (size_t)DM * DM;
  u16* wsu = (u16*)d_ws;
  u16* qh = wsu;
  u16* kh = wsu + PLANE;
  u16* vt = wsu + 2 * PLANE;
  u16* fcwb = wsu + 3 * PLANE;
  float* ctx = out0;

  u16* satt = (u16*)attn_out;
  u16* qxb = satt;
  u16* kxb = satt + PLANE;
  u16* vxb = satt + 2 * PLANE;
  u16* wqb = satt + 3 * PLANE;
  u16* wkb = satt + 3 * PLANE + WSZ;
  u16* wvb = satt + 3 * PLANE + 2 * WSZ;

  float* fcout = (float*)d_ws;

  cvt_all<<<4096, 256, 0, stream>>>(q, k, v, w_qs, w_ks, w_vs, fcw,
                                    qxb, kxb, vxb, wqb, wkb, wvb, fcwb);
  gemm_proj<<<768, 256, 0, stream>>>(qxb, kxb, vxb, wqb, wkb, wvb,
                                     b_qs, b_ks, b_vs, seq_len, qh, kh, vt);
  attn_kernel<<<dim3(64, 64), 256, 0, stream>>>(qh, kh, vt, seq_len, attn_out, ctx);
  gemm_fc<<<256, 256, 0, stream>>>(ctx, fcwb, fcb, q, seq_len, fcout);
  ln_rows<<<1024, 256, 0, stream>>>(fcout, lng, lnb, out0);
}